// Round 2
// baseline (756.693 us; speedup 1.0000x reference)
//
#include <hip/hip_runtime.h>

#define NN 100000
#define NE 1600000

// ---------------- CSR build ----------------

__global__ void k_deg(const int* __restrict__ dst, int* __restrict__ deg, int E) {
    int i = blockIdx.x * blockDim.x + threadIdx.x;
    if (i < E) atomicAdd(&deg[dst[i]], 1);
}

// block-level exclusive scan: 1024 elems/block (256 thr x 4)
__global__ void k_scan1(const int* __restrict__ deg, int* __restrict__ offs,
                        int* __restrict__ bsums, int n) {
    __shared__ int sh[256];
    int t = threadIdx.x;
    int base = blockIdx.x * 1024 + t * 4;
    int v0 = 0, v1 = 0, v2 = 0, v3 = 0;
    if (base + 0 < n) v0 = deg[base + 0];
    if (base + 1 < n) v1 = deg[base + 1];
    if (base + 2 < n) v2 = deg[base + 2];
    if (base + 3 < n) v3 = deg[base + 3];
    int s = v0 + v1 + v2 + v3;
    sh[t] = s;
    __syncthreads();
    for (int off = 1; off < 256; off <<= 1) {
        int x = (t >= off) ? sh[t - off] : 0;
        __syncthreads();
        sh[t] += x;
        __syncthreads();
    }
    int run = sh[t] - s;  // exclusive base for this thread
    if (base + 0 < n) { offs[base + 0] = run; run += v0; }
    if (base + 1 < n) { offs[base + 1] = run; run += v1; }
    if (base + 2 < n) { offs[base + 2] = run; run += v2; }
    if (base + 3 < n) { offs[base + 3] = run; run += v3; }
    if (t == 255) bsums[blockIdx.x] = sh[255];
}

__global__ void k_scan2(int* __restrict__ bsums, int nb) {
    if (blockIdx.x == 0 && threadIdx.x == 0) {
        int run = 0;
        for (int i = 0; i < nb; ++i) { int v = bsums[i]; bsums[i] = run; run += v; }
    }
}

__global__ void k_scan3(int* __restrict__ offs, int* __restrict__ cursor,
                        const int* __restrict__ bsums, int n, int E) {
    int i = blockIdx.x * blockDim.x + threadIdx.x;
    if (i < n) {
        int v = offs[i] + bsums[i >> 10];
        offs[i] = v;
        cursor[i] = v;
    }
    if (i == 0) offs[n] = E;
}

__global__ void k_scatter(const int* __restrict__ src, const int* __restrict__ dst,
                          int* __restrict__ cursor, int* __restrict__ csr, int E) {
    int i = blockIdx.x * blockDim.x + threadIdx.x;
    if (i < E) {
        int d = dst[i];
        int p = atomicAdd(&cursor[d], 1);
        csr[p] = src[i];
    }
}

// ---------------- GEMM: Y[M, Ofull] = X[M,128] @ W[O,128]^T (+bias) ----------------
// BM=64, BO=64, KK=64, 256 threads, 4x4 acc/thread. LDS pad 65 -> <=2-way conflicts (free).

__launch_bounds__(256)
__global__ void k_gemm(const float* __restrict__ X, const float* __restrict__ W,
                       const float* __restrict__ bias, float* __restrict__ Y,
                       int M, int Ofull) {
    __shared__ float xs[64][65];
    __shared__ float wsm[64][65];
    int t = threadIdx.x;
    int bm = blockIdx.x * 64;
    int bo = blockIdx.y * 64;
    int tr = t >> 4, tc = t & 15;
    float acc[4][4] = {};

    for (int ko = 0; ko < 128; ko += 64) {
        #pragma unroll
        for (int i = 0; i < 4; ++i) {
            int u = t + i * 256;         // float4 unit among 64x16
            int r = u >> 4;
            int c = (u & 15) * 4;
            int gr = bm + r;
            float4 xv = (gr < M) ? *(const float4*)(X + (size_t)gr * 128 + ko + c)
                                 : make_float4(0.f, 0.f, 0.f, 0.f);
            xs[r][c + 0] = xv.x; xs[r][c + 1] = xv.y; xs[r][c + 2] = xv.z; xs[r][c + 3] = xv.w;
            float4 wv = *(const float4*)(W + (size_t)(bo + r) * 128 + ko + c);
            wsm[r][c + 0] = wv.x; wsm[r][c + 1] = wv.y; wsm[r][c + 2] = wv.z; wsm[r][c + 3] = wv.w;
        }
        __syncthreads();
        #pragma unroll
        for (int k = 0; k < 64; ++k) {
            float a0 = xs[tr * 4 + 0][k];
            float a1 = xs[tr * 4 + 1][k];
            float a2 = xs[tr * 4 + 2][k];
            float a3 = xs[tr * 4 + 3][k];
            float b0 = wsm[tc * 4 + 0][k];
            float b1 = wsm[tc * 4 + 1][k];
            float b2 = wsm[tc * 4 + 2][k];
            float b3 = wsm[tc * 4 + 3][k];
            acc[0][0] = fmaf(a0, b0, acc[0][0]); acc[0][1] = fmaf(a0, b1, acc[0][1]);
            acc[0][2] = fmaf(a0, b2, acc[0][2]); acc[0][3] = fmaf(a0, b3, acc[0][3]);
            acc[1][0] = fmaf(a1, b0, acc[1][0]); acc[1][1] = fmaf(a1, b1, acc[1][1]);
            acc[1][2] = fmaf(a1, b2, acc[1][2]); acc[1][3] = fmaf(a1, b3, acc[1][3]);
            acc[2][0] = fmaf(a2, b0, acc[2][0]); acc[2][1] = fmaf(a2, b1, acc[2][1]);
            acc[2][2] = fmaf(a2, b2, acc[2][2]); acc[2][3] = fmaf(a2, b3, acc[2][3]);
            acc[3][0] = fmaf(a3, b0, acc[3][0]); acc[3][1] = fmaf(a3, b1, acc[3][1]);
            acc[3][2] = fmaf(a3, b2, acc[3][2]); acc[3][3] = fmaf(a3, b3, acc[3][3]);
        }
        __syncthreads();
    }

    float4 bv = make_float4(0.f, 0.f, 0.f, 0.f);
    if (bias) bv = *(const float4*)(bias + bo + tc * 4);
    #pragma unroll
    for (int i = 0; i < 4; ++i) {
        int gr = bm + tr * 4 + i;
        if (gr < M) {
            float4 o = make_float4(acc[i][0] + bv.x, acc[i][1] + bv.y,
                                   acc[i][2] + bv.z, acc[i][3] + bv.w);
            *(float4*)(Y + (size_t)gr * Ofull + bo + tc * 4) = o;
        }
    }
}

// ---------------- Aggregation ----------------
// one wave per dst node; lane-parallel over feature dim.
// layer1: D=128 (2 floats/lane); h = relu(agg*inv + xr1b) computed in-place on xr1b.

__launch_bounds__(256)
__global__ void k_agg1(const float* __restrict__ xl1, float* __restrict__ h,
                       const int* __restrict__ csr, const int* __restrict__ offs) {
    int node = blockIdx.x * 4 + (threadIdx.x >> 6);
    if (node >= NN) return;
    int lane = threadIdx.x & 63;
    int s = offs[node], e = offs[node + 1];
    float a0 = 0.f, a1 = 0.f;
    for (int i = s; i < e; ++i) {
        int src = csr[i];
        float2 v = *((const float2*)(xl1 + (size_t)src * 128) + lane);
        a0 += v.x; a1 += v.y;
    }
    float inv = 1.0f / fmaxf((float)(e - s), 1.0f);
    float2* hp = (float2*)(h + (size_t)node * 128) + lane;
    float2 r = *hp;
    r.x = fmaxf(fmaf(a0, inv, r.x), 0.0f);
    r.y = fmaxf(fmaf(a1, inv, r.y), 0.0f);
    *hp = r;
}

// layer2: D=64 (1 float/lane); out += agg*inv, in-place on d_out (already holds h@w_r2.T + b2)
__launch_bounds__(256)
__global__ void k_agg2(const float* __restrict__ hl2, float* __restrict__ out,
                       const int* __restrict__ csr, const int* __restrict__ offs) {
    int node = blockIdx.x * 4 + (threadIdx.x >> 6);
    if (node >= NN) return;
    int lane = threadIdx.x & 63;
    int s = offs[node], e = offs[node + 1];
    float a = 0.f;
    for (int i = s; i < e; ++i) {
        int src = csr[i];
        a += hl2[(size_t)src * 64 + lane];
    }
    float inv = 1.0f / fmaxf((float)(e - s), 1.0f);
    float* op = out + (size_t)node * 64 + lane;
    *op = fmaf(a, inv, *op);
}

// ---------------- launch ----------------

extern "C" void kernel_launch(void* const* d_in, const int* in_sizes, int n_in,
                              void* d_out, int out_size, void* d_ws, size_t ws_size,
                              hipStream_t stream) {
    const float* x        = (const float*)d_in[0];
    const int* ei         = (const int*)d_in[1];   // int64 in reference -> int32 here (harness contract)
    const float* w_l1     = (const float*)d_in[2];
    const float* w_r1     = (const float*)d_in[3];
    const float* b1       = (const float*)d_in[4];
    const float* w_l2     = (const float*)d_in[5];
    const float* w_r2     = (const float*)d_in[6];
    const float* b2       = (const float*)d_in[7];
    float* out            = (float*)d_out;

    const int* esrc = ei;        // edge_index[0]
    const int* edst = ei + NE;   // edge_index[1]

    // workspace layout (~110 MB)
    float* xl1  = (float*)d_ws;            // NN*128  (later reused as hl2, NN*64)
    float* xr1b = xl1 + (size_t)NN * 128;  // NN*128  (becomes h in-place)
    int* csr    = (int*)(xr1b + (size_t)NN * 128);  // NE
    int* deg    = csr + NE;                // NN
    int* offs   = deg + NN;                // NN+1
    int* cursor = offs + NN + 1;           // NN
    int* bsums  = cursor + NN;             // 128

    // ---- CSR build ----
    hipMemsetAsync(deg, 0, NN * sizeof(int), stream);
    k_deg<<<(NE + 255) / 256, 256, 0, stream>>>(edst, deg, NE);
    int nb = (NN + 1023) / 1024;
    k_scan1<<<nb, 256, 0, stream>>>(deg, offs, bsums, NN);
    k_scan2<<<1, 64, 0, stream>>>(bsums, nb);
    k_scan3<<<(NN + 255) / 256, 256, 0, stream>>>(offs, cursor, bsums, NN, NE);
    k_scatter<<<(NE + 255) / 256, 256, 0, stream>>>(esrc, edst, cursor, csr, NE);

    // ---- layer 1: xl1 = x@w_l1^T ; xr1b = x@w_r1^T + b1 ; h = relu(agg(xl1)/deg + xr1b) ----
    dim3 g1((NN + 63) / 64, 2);
    k_gemm<<<g1, 256, 0, stream>>>(x, w_l1, nullptr, xl1, NN, 128);
    k_gemm<<<g1, 256, 0, stream>>>(x, w_r1, b1, xr1b, NN, 128);
    k_agg1<<<(NN + 3) / 4, 256, 0, stream>>>(xl1, xr1b, csr, offs);

    // ---- layer 2: hl2 = h@w_l2^T ; out = h@w_r2^T + b2 ; out += agg(hl2)/deg ----
    dim3 g2((NN + 63) / 64, 1);
    k_gemm<<<g2, 256, 0, stream>>>(xr1b, w_l2, nullptr, xl1, NN, 64);
    k_gemm<<<g2, 256, 0, stream>>>(xr1b, w_r2, b2, out, NN, 64);
    k_agg2<<<(NN + 3) / 4, 256, 0, stream>>>(xl1, out, csr, offs);
}

// Round 3
// 418.928 us; speedup vs baseline: 1.8063x; 1.8063x over previous
//
#include <hip/hip_runtime.h>

#define NN 100000
#define NE 1600000

typedef _Float16 f16;
typedef _Float16 f16x8 __attribute__((ext_vector_type(8)));
typedef float f32x4 __attribute__((ext_vector_type(4)));

static __device__ __forceinline__ float h2f_lo(unsigned v) {
    return (float)__builtin_bit_cast(_Float16, (unsigned short)(v & 0xffffu));
}
static __device__ __forceinline__ float h2f_hi(unsigned v) {
    return (float)__builtin_bit_cast(_Float16, (unsigned short)(v >> 16));
}
static __device__ __forceinline__ unsigned f2h_bits(float f) {
    return (unsigned)__builtin_bit_cast(unsigned short, (_Float16)f);
}

// ---------------- f32 -> f16 conversion (8 elems/thread) ----------------

__global__ void k_cvt(const float* __restrict__ in, f16* __restrict__ out, int n) {
    int i = (blockIdx.x * blockDim.x + threadIdx.x) * 8;
    if (i >= n) return;
    float4 a = *(const float4*)(in + i);
    float4 b = *(const float4*)(in + i + 4);
    f16x8 v = { (f16)a.x, (f16)a.y, (f16)a.z, (f16)a.w,
                (f16)b.x, (f16)b.y, (f16)b.z, (f16)b.w };
    *(f16x8*)(out + i) = v;
}

// ---------------- CSR build ----------------

__global__ void k_deg(const int* __restrict__ dst, int* __restrict__ deg, int E) {
    int i = blockIdx.x * blockDim.x + threadIdx.x;
    if (i < E) atomicAdd(&deg[dst[i]], 1);
}

__global__ void k_scan1(const int* __restrict__ deg, int* __restrict__ offs,
                        int* __restrict__ bsums, int n) {
    __shared__ int sh[256];
    int t = threadIdx.x;
    int base = blockIdx.x * 1024 + t * 4;
    int v0 = 0, v1 = 0, v2 = 0, v3 = 0;
    if (base + 0 < n) v0 = deg[base + 0];
    if (base + 1 < n) v1 = deg[base + 1];
    if (base + 2 < n) v2 = deg[base + 2];
    if (base + 3 < n) v3 = deg[base + 3];
    int s = v0 + v1 + v2 + v3;
    sh[t] = s;
    __syncthreads();
    for (int off = 1; off < 256; off <<= 1) {
        int x = (t >= off) ? sh[t - off] : 0;
        __syncthreads();
        sh[t] += x;
        __syncthreads();
    }
    int run = sh[t] - s;
    if (base + 0 < n) { offs[base + 0] = run; run += v0; }
    if (base + 1 < n) { offs[base + 1] = run; run += v1; }
    if (base + 2 < n) { offs[base + 2] = run; run += v2; }
    if (base + 3 < n) { offs[base + 3] = run; run += v3; }
    if (t == 255) bsums[blockIdx.x] = sh[255];
}

__global__ void k_scan2(int* __restrict__ bsums, int nb) {
    if (blockIdx.x == 0 && threadIdx.x == 0) {
        int run = 0;
        for (int i = 0; i < nb; ++i) { int v = bsums[i]; bsums[i] = run; run += v; }
    }
}

__global__ void k_scan3(int* __restrict__ offs, int* __restrict__ cursor,
                        const int* __restrict__ bsums, int n, int E) {
    int i = blockIdx.x * blockDim.x + threadIdx.x;
    if (i < n) {
        int v = offs[i] + bsums[i >> 10];
        offs[i] = v;
        cursor[i] = v;
    }
    if (i == 0) offs[n] = E;
}

__global__ void k_scatter(const int* __restrict__ src, const int* __restrict__ dst,
                          int* __restrict__ cursor, int* __restrict__ csr, int E) {
    int i = blockIdx.x * blockDim.x + threadIdx.x;
    if (i < E) {
        int d = dst[i];
        int p = atomicAdd(&cursor[d], 1);
        csr[p] = src[i];
    }
}

// ---------------- MFMA GEMM: Y[M, 2*N0] = X[M,128] @ Wcat[2*N0,128]^T ----------------
// blockIdx.y = 0: cols [0,N0)    -> Yl (f16, no bias)     [lin_l output, pre-aggregation]
// blockIdx.y = 1: cols [N0,2N0)  -> Yr (f32, + bias)      [lin_r output + b]
// 4 waves/block, 16 rows each; W half staged in LDS, row stride 272B (2-way = free).
// Fragment layouts (m89-verified): A lane l -> X[l&15][(l>>4)*8+j]; B lane l -> W[l&15][(l>>4)*8+j];
// D lane l, reg r -> row (l>>4)*4+r, col l&15.

template<int NT>
__launch_bounds__(256)
__global__ void k_gemm_mfma(const f16* __restrict__ X, const f16* __restrict__ Wcat,
                            const float* __restrict__ bias,
                            f16* __restrict__ Yl, float* __restrict__ Yr, int M) {
    constexpr int N0 = NT * 16;
    __shared__ __align__(16) char wlds[N0 * 272];

    const f16* wsrc = Wcat + (size_t)blockIdx.y * N0 * 128;
    for (int u = threadIdx.x; u < N0 * 16; u += 256) {
        int r = u >> 4, c = u & 15;
        *(uint4*)(wlds + r * 272 + c * 16) = *(const uint4*)(wsrc + r * 128 + c * 8);
    }
    __syncthreads();

    int l = threadIdx.x & 63;
    int wid = threadIdx.x >> 6;
    int bm = blockIdx.x * 64;
    int arow = bm + wid * 16 + (l & 15);
    if (arow >= M) arow = M - 1;          // tail: compute junk rows, don't store
    int kq = (l >> 4) * 8;                // per-lane k sub-offset within a 32-chunk

    f32x4 acc[NT];
    #pragma unroll
    for (int n = 0; n < NT; ++n) acc[n] = (f32x4){0.f, 0.f, 0.f, 0.f};

    #pragma unroll
    for (int ks = 0; ks < 4; ++ks) {
        f16x8 av = *(const f16x8*)(X + (size_t)arow * 128 + ks * 32 + kq);
        #pragma unroll
        for (int n = 0; n < NT; ++n) {
            f16x8 bv = *(const f16x8*)(wlds + (n * 16 + (l & 15)) * 272 + ks * 64 + kq * 2);
            acc[n] = __builtin_amdgcn_mfma_f32_16x16x32_f16(av, bv, acc[n], 0, 0, 0);
        }
    }

    int row0 = bm + wid * 16 + (l >> 4) * 4;
    int col = l & 15;
    if (blockIdx.y == 0) {
        #pragma unroll
        for (int n = 0; n < NT; ++n) {
            #pragma unroll
            for (int r = 0; r < 4; ++r) {
                int gr = row0 + r;
                if (gr < M) Yl[(size_t)gr * N0 + n * 16 + col] = (f16)acc[n][r];
            }
        }
    } else {
        #pragma unroll
        for (int n = 0; n < NT; ++n) {
            float bv = bias ? bias[n * 16 + col] : 0.f;
            #pragma unroll
            for (int r = 0; r < 4; ++r) {
                int gr = row0 + r;
                if (gr < M) Yr[(size_t)gr * N0 + n * 16 + col] = acc[n][r] + bv;
            }
        }
    }
}

// ---------------- Aggregation (mean over in-edges), f16 gather, f32 accum ----------------
// one wave per dst node; unroll x4 to keep 4 gather rows in flight.

__launch_bounds__(256)
__global__ void k_agg1(const unsigned* __restrict__ xl1, const float* __restrict__ xr1b,
                       unsigned* __restrict__ h,
                       const int* __restrict__ csr, const int* __restrict__ offs) {
    int node = blockIdx.x * 4 + (threadIdx.x >> 6);
    if (node >= NN) return;
    int lane = threadIdx.x & 63;
    int s = offs[node], e = offs[node + 1];
    float a0 = 0.f, a1 = 0.f;
    int i = s;
    for (; i + 4 <= e; i += 4) {
        int s0 = csr[i], s1 = csr[i + 1], s2 = csr[i + 2], s3 = csr[i + 3];
        unsigned v0 = xl1[(size_t)s0 * 64 + lane];
        unsigned v1 = xl1[(size_t)s1 * 64 + lane];
        unsigned v2 = xl1[(size_t)s2 * 64 + lane];
        unsigned v3 = xl1[(size_t)s3 * 64 + lane];
        a0 += h2f_lo(v0) + h2f_lo(v1) + h2f_lo(v2) + h2f_lo(v3);
        a1 += h2f_hi(v0) + h2f_hi(v1) + h2f_hi(v2) + h2f_hi(v3);
    }
    for (; i < e; ++i) {
        unsigned v = xl1[(size_t)csr[i] * 64 + lane];
        a0 += h2f_lo(v); a1 += h2f_hi(v);
    }
    float inv = 1.0f / fmaxf((float)(e - s), 1.0f);
    float2 xr = ((const float2*)(xr1b + (size_t)node * 128))[lane];
    float r0 = fmaxf(fmaf(a0, inv, xr.x), 0.0f);
    float r1 = fmaxf(fmaf(a1, inv, xr.y), 0.0f);
    h[(size_t)node * 64 + lane] = f2h_bits(r0) | (f2h_bits(r1) << 16);
}

__launch_bounds__(256)
__global__ void k_agg2(const unsigned short* __restrict__ hl2, float* __restrict__ out,
                       const int* __restrict__ csr, const int* __restrict__ offs) {
    int node = blockIdx.x * 4 + (threadIdx.x >> 6);
    if (node >= NN) return;
    int lane = threadIdx.x & 63;
    int s = offs[node], e = offs[node + 1];
    float a = 0.f;
    int i = s;
    for (; i + 4 <= e; i += 4) {
        int s0 = csr[i], s1 = csr[i + 1], s2 = csr[i + 2], s3 = csr[i + 3];
        float v0 = (float)__builtin_bit_cast(_Float16, hl2[(size_t)s0 * 64 + lane]);
        float v1 = (float)__builtin_bit_cast(_Float16, hl2[(size_t)s1 * 64 + lane]);
        float v2 = (float)__builtin_bit_cast(_Float16, hl2[(size_t)s2 * 64 + lane]);
        float v3 = (float)__builtin_bit_cast(_Float16, hl2[(size_t)s3 * 64 + lane]);
        a += v0 + v1 + v2 + v3;
    }
    for (; i < e; ++i)
        a += (float)__builtin_bit_cast(_Float16, hl2[(size_t)csr[i] * 64 + lane]);
    float inv = 1.0f / fmaxf((float)(e - s), 1.0f);
    float* op = out + (size_t)node * 64 + lane;
    *op = fmaf(a, inv, *op);
}

// ---------------- launch ----------------

extern "C" void kernel_launch(void* const* d_in, const int* in_sizes, int n_in,
                              void* d_out, int out_size, void* d_ws, size_t ws_size,
                              hipStream_t stream) {
    const float* x    = (const float*)d_in[0];
    const int* ei     = (const int*)d_in[1];   // int64 ref -> int32 at the harness boundary
    const float* w_l1 = (const float*)d_in[2];
    const float* w_r1 = (const float*)d_in[3];
    const float* b1   = (const float*)d_in[4];
    const float* w_l2 = (const float*)d_in[5];
    const float* w_r2 = (const float*)d_in[6];
    const float* b2   = (const float*)d_in[7];
    float* out        = (float*)d_out;

    const int* esrc = ei;
    const int* edst = ei + NE;

    // workspace layout (~110 MB)
    float* xr1b = (float*)d_ws;                       // NN*128 f32
    f16*   xb   = (f16*)(xr1b + (size_t)NN * 128);    // NN*128 f16; later reused as h
    f16*   xl1h = xb + (size_t)NN * 128;              // NN*128 f16; later reused as hl2
    f16*   W1   = xl1h + (size_t)NN * 128;            // 256*128 f16 = [w_l1; w_r1]
    f16*   W2   = W1 + 256 * 128;                     // 128*128 f16 = [w_l2; w_r2]
    int*   csr  = (int*)(W2 + 128 * 128);             // NE
    int*   deg    = csr + NE;                         // NN
    int*   offs   = deg + NN;                         // NN+1
    int*   cursor = offs + NN + 1;                    // NN
    int*   bsums  = cursor + NN;                      // 128

    f16* h    = xb;     // alias: xb dead after GEMM1
    f16* hl2h = xl1h;   // alias: xl1h dead after agg1

    // ---- conversions to f16 ----
    k_cvt<<<(NN * 128 / 8 + 255) / 256, 256, 0, stream>>>(x, xb, NN * 128);
    k_cvt<<<8, 256, 0, stream>>>(w_l1, W1, 128 * 128);
    k_cvt<<<8, 256, 0, stream>>>(w_r1, W1 + 128 * 128, 128 * 128);
    k_cvt<<<4, 256, 0, stream>>>(w_l2, W2, 64 * 128);
    k_cvt<<<4, 256, 0, stream>>>(w_r2, W2 + 64 * 128, 64 * 128);

    // ---- CSR build ----
    hipMemsetAsync(deg, 0, NN * sizeof(int), stream);
    k_deg<<<(NE + 255) / 256, 256, 0, stream>>>(edst, deg, NE);
    int nb = (NN + 1023) / 1024;
    k_scan1<<<nb, 256, 0, stream>>>(deg, offs, bsums, NN);
    k_scan2<<<1, 64, 0, stream>>>(bsums, nb);
    k_scan3<<<(NN + 255) / 256, 256, 0, stream>>>(offs, cursor, bsums, NN, NE);
    k_scatter<<<(NE + 255) / 256, 256, 0, stream>>>(esrc, edst, cursor, csr, NE);

    // ---- layer 1: [xl1h | xr1b] = xb @ [w_l1; w_r1]^T (+b1 on r-path); h = relu(agg+xr1b) ----
    dim3 g1((NN + 63) / 64, 2);
    k_gemm_mfma<8><<<g1, 256, 0, stream>>>(xb, W1, b1, xl1h, xr1b, NN);
    k_agg1<<<(NN + 3) / 4, 256, 0, stream>>>((const unsigned*)xl1h, xr1b, (unsigned*)h, csr, offs);

    // ---- layer 2: [hl2h | out] = h @ [w_l2; w_r2]^T (+b2 on r-path); out += agg(hl2h) ----
    dim3 g2((NN + 63) / 64, 2);
    k_gemm_mfma<4><<<g2, 256, 0, stream>>>(h, W2, b2, hl2h, out, NN);
    k_agg2<<<(NN + 3) / 4, 256, 0, stream>>>((const unsigned short*)hl2h, out, csr, offs);
}